// Round 3
// baseline (2917.300 us; speedup 1.0000x reference)
//
#include <hip/hip_runtime.h>
#include <hip/hip_bf16.h>

typedef __bf16 bf16;
typedef __attribute__((ext_vector_type(8))) __bf16 bf16x8;
typedef __attribute__((ext_vector_type(4))) float f32x4;
typedef __attribute__((ext_vector_type(2))) float f32x2;

// Pack two f32x4 into a bf16x8 MFMA fragment (round-to-nearest via cast).
static __device__ inline bf16x8 pack_bf16x8(f32x4 lo, f32x4 hi) {
    bf16x8 t;
#pragma unroll
    for (int j = 0; j < 4; ++j) {
        t[j]     = (__bf16)lo[j];
        t[4 + j] = (__bf16)hi[j];
    }
    return t;
}

// ---------------------------------------------------------------------------
// Scatter-mean accumulation for destination rows in [lo, hi): one wave per
// edge. Lane i handles elements [2i, 2i+1] (float2) of the 128-wide row.
// agg/cnt are fp32, indexed by (d - lo) so the chunk fits in ws_size.
// ---------------------------------------------------------------------------
__global__ __launch_bounds__(256)
void scatter_kernel(const float* __restrict__ xsrc,
                    const int* __restrict__ si,
                    const int* __restrict__ di,
                    float* __restrict__ agg,
                    float* __restrict__ cnt,
                    int E, int lo, int hi) {
    int lane = threadIdx.x & 63;
    int wid = (int)((blockIdx.x * (unsigned)blockDim.x + threadIdx.x) >> 6);
    if (wid >= E) return;
    int d = di[wid];
    if (d < lo || d >= hi) return;
    int s = si[wid];
    const f32x2* row = (const f32x2*)(xsrc + (size_t)s * 128);
    f32x2 v = row[lane];
    float* arow = agg + (size_t)(d - lo) * 128 + lane * 2;
    unsafeAtomicAdd(arow, v.x);
    unsafeAtomicAdd(arow + 1, v.y);
    if (lane == 0) unsafeAtomicAdd(cnt + (d - lo), 1.0f);
}

// ---------------------------------------------------------------------------
// Fused: out_row = L2norm( x_dst@WL^T + b + (agg/cnt)@WR^T ) for rows
// [lo, hi), optional += into existing fp32 output. Block = 4 waves; wave
// handles 16 rows x 128 cols via 8 col-tiles of mfma_f32_16x16x32_bf16
// (shared accumulator chains both GEMMs). All global I/O fp32; bf16 only
// as MFMA operands.
// ---------------------------------------------------------------------------
__global__ __launch_bounds__(256)
void sage_gemm(const float* __restrict__ xdst,
               const float* __restrict__ agg,
               const float* __restrict__ cnt,
               const float* __restrict__ wl,
               const float* __restrict__ wr,
               const float* __restrict__ bias,
               float* __restrict__ outp,
               int lo, int hi, int accumulate) {
    int lane = threadIdx.x & 63;
    int wave = threadIdx.x >> 6;
    int m = lane & 15;   // A row within tile / C col within tile
    int q = lane >> 4;   // quad
    int nloc = hi - lo;
    int r0 = blockIdx.x * 64 + wave * 16;            // local row base
    int rl = min(r0 + m, nloc - 1);                  // clamped local load row
    int rowg = lo + rl;                              // global row

    // A1 fragments: x_dst rows (fp32 -> bf16). A[m=lane&15][k=q*8+j]
    bf16x8 a1[4];
    const f32x4* xrow = (const f32x4*)(xdst + (size_t)rowg * 128);
#pragma unroll
    for (int kc = 0; kc < 4; ++kc)
        a1[kc] = pack_bf16x8(xrow[kc * 8 + q * 2], xrow[kc * 8 + q * 2 + 1]);

    // A2 fragments: (agg/cnt) local rows (fp32 -> bf16)
    float invc = 1.0f / fmaxf(cnt[rl], 1.0f);
    bf16x8 a2[4];
    const f32x4* arow = (const f32x4*)(agg + (size_t)rl * 128);
#pragma unroll
    for (int kc = 0; kc < 4; ++kc) {
        f32x4 vlo = arow[kc * 8 + q * 2];
        f32x4 vhi = arow[kc * 8 + q * 2 + 1];
        bf16x8 t;
#pragma unroll
        for (int j = 0; j < 4; ++j) {
            t[j]     = (__bf16)(vlo[j] * invc);
            t[4 + j] = (__bf16)(vhi[j] * invc);
        }
        a2[kc] = t;
    }

    // 8 col-tiles; B[k][n] = W[n][k]: lane reads W row (n = ct*16+m)
    f32x4 acc[8];
#pragma unroll
    for (int ct = 0; ct < 8; ++ct) {
        f32x4 c = {0.f, 0.f, 0.f, 0.f};
        const f32x4* wlr = (const f32x4*)(wl + (size_t)(ct * 16 + m) * 128);
        const f32x4* wrr = (const f32x4*)(wr + (size_t)(ct * 16 + m) * 128);
#pragma unroll
        for (int kc = 0; kc < 4; ++kc) {
            bf16x8 bl = pack_bf16x8(wlr[kc * 8 + q * 2], wlr[kc * 8 + q * 2 + 1]);
            bf16x8 br = pack_bf16x8(wrr[kc * 8 + q * 2], wrr[kc * 8 + q * 2 + 1]);
            c = __builtin_amdgcn_mfma_f32_16x16x32_bf16(a1[kc], bl, c, 0, 0, 0);
            c = __builtin_amdgcn_mfma_f32_16x16x32_bf16(a2[kc], br, c, 0, 0, 0);
        }
        acc[ct] = c;
    }

    // Epilogue: +bias, per-row L2 norm (row lives across a 16-lane group),
    // normalize, store fp32 (optionally accumulating previous sage's output).
    float y[8][4];
    float ss[4] = {0.f, 0.f, 0.f, 0.f};
#pragma unroll
    for (int ct = 0; ct < 8; ++ct) {
        float bb = bias[ct * 16 + m];
#pragma unroll
        for (int r = 0; r < 4; ++r) {
            float v = acc[ct][r] + bb;
            y[ct][r] = v;
            ss[r] += v * v;
        }
    }
#pragma unroll
    for (int off = 1; off < 16; off <<= 1) {
#pragma unroll
        for (int r = 0; r < 4; ++r) ss[r] += __shfl_xor(ss[r], off);
    }
    float sc[4];
#pragma unroll
    for (int r = 0; r < 4; ++r) sc[r] = 1.0f / fmaxf(sqrtf(ss[r]), 1e-12f);

#pragma unroll
    for (int r = 0; r < 4; ++r) {
        int ol = r0 + q * 4 + r;  // C/D: row = quad*4 + reg (local)
        if (ol < nloc) {
            size_t base = (size_t)(lo + ol) * 128 + m;
#pragma unroll
            for (int ct = 0; ct < 8; ++ct) {
                float v = y[ct][r] * sc[r];
                size_t idx = base + (size_t)ct * 16;
                if (accumulate) v += outp[idx];
                outp[idx] = v;
            }
        }
    }
}

extern "C" void kernel_launch(void* const* d_in, const int* in_sizes, int n_in,
                              void* d_out, int out_size, void* d_ws, size_t ws_size,
                              hipStream_t stream) {
    const int D = 128;
    const float* x_article = (const float*)d_in[0];
    const float* x_entity  = (const float*)d_in[1];
    const float* x_fact    = (const float*)d_in[2];
    int NA = in_sizes[0] / D;
    int NE = in_sizes[1] / D;
    int NF = in_sizes[2] / D;

    const int* si[5];
    const int* di[5];
    for (int i = 0; i < 5; ++i) {
        si[i] = (const int*)d_in[3 + 2 * i];
        di[i] = (const int*)d_in[4 + 2 * i];
    }
    const float *wl[5], *bia[5], *wr[5];
    for (int i = 0; i < 5; ++i) {
        wl[i]  = (const float*)d_in[13 + 3 * i];
        bia[i] = (const float*)d_in[14 + 3 * i];
        wr[i]  = (const float*)d_in[15 + 3 * i];
    }

    float* outp = (float*)d_out;
    float* out_article = outp;
    float* out_entity  = outp + (size_t)NA * D;
    float* out_fact    = outp + (size_t)(NA + NE) * D;

    // EDGE_TYPES: (art->ent), (art->fact), (ent->art), (ent->fact), (fact->ent)
    const float* xsrc[5] = {x_article, x_article, x_entity, x_entity, x_fact};
    const float* xdst[5] = {x_entity, x_fact, x_article, x_fact, x_entity};
    int ndst[5]    = {NE, NF, NA, NF, NE};
    float* outs[5] = {out_entity, out_fact, out_article, out_fact, out_entity};
    int accs[5]    = {0, 0, 0, 1, 1};

    // Chunk destination rows so fp32 agg[cr*128] + cnt[cr] ALWAYS fits ws_size.
    float* agg = (float*)d_ws;
    long long max_rows = (long long)(ws_size / sizeof(float)) / (D + 1);
    if (max_rows < 64) max_rows = 64;  // ws_size is at least a few MB in practice

    for (int t = 0; t < 5; ++t) {
        int nd = ndst[t];
        int E = in_sizes[3 + 2 * t];
        for (int lo = 0; lo < nd; lo += (int)max_rows) {
            int hi = nd - lo < max_rows ? nd : lo + (int)max_rows;
            int cr = hi - lo;
            float* cnt = agg + (size_t)cr * D;
            hipMemsetAsync(d_ws, 0, (size_t)cr * (D + 1) * sizeof(float), stream);
            int sblocks = (E + 3) / 4;  // 4 waves/block, 1 wave per edge
            scatter_kernel<<<sblocks, 256, 0, stream>>>(xsrc[t], si[t], di[t], agg, cnt,
                                                        E, lo, hi);
            int gblocks = (cr + 63) / 64;
            sage_gemm<<<gblocks, 256, 0, stream>>>(xdst[t], agg, cnt, wl[t], wr[t], bia[t],
                                                   outs[t], lo, hi, accs[t]);
        }
    }
}